// Round 11
// baseline (231.341 us; speedup 1.0000x reference)
//
#include <hip/hip_runtime.h>

// DAG MLP: L=8 layers, D=64, B=262144, 28 all-to-all forward connections.
// outs[j] += relu(outs[i] @ W_c^T + b_c), output = outs[7].
// v11 = v8 (best: 102us) made PERSISTENT with a seamless cross-tile W ring:
//   - grid 768 (3 blocks/CU), grid-stride over 4096 tiles of 64 rows
//   - the 4-slot ring schedule wraps across tiles (28 % 4 == 0): period p=26
//     stages next tile's conns (0,1) into slots (0,1); p=0 stages (2,3).
//     The gll pipeline NEVER drains cold after the one-time prologue.
//   - bias LDS staged once per block (was: once per 64-row tile)
//   - inner structure identical to v8: 2 pairs x 32 rows, feature-split
//     waves, pair __syncthreads, pre-swizzled bf16 W image via
//     global_load_lds(16B), setprio, MFMA-carried accumulation
//     C_in=acc+b; acc=max(D,acc) == acc+relu(S+b), lgkm-only bounce barriers.

#define DD 64
#define NCONN 28
#define THREADS 256
#define ROWS_PER_TILE 64       // 2 pairs * 32 rows
#define NTILES 4096            // 262144 / 64
#define GRIDB 768              // 3 blocks/CU * 256 CU
#define MAT_ELEMS 4096         // 64*64

typedef __bf16 bf16x8 __attribute__((ext_vector_type(8)));
typedef float f32x4 __attribute__((ext_vector_type(4)));
typedef unsigned short u16x8 __attribute__((ext_vector_type(8)));

// c(i->j) = OFFS[i] + (j-i-1); CONN[p] = connection at compute position p
// (phases j=1..7, sources i ascending within phase).
__device__ constexpr int OFFS[7] = {0, 7, 13, 18, 22, 25, 27};
__device__ constexpr int CONN[28] = {0, 1,7, 2,8,13, 3,9,14,18, 4,10,15,19,22,
                                     5,11,16,20,23,25, 6,12,17,21,24,26,27};

__device__ __forceinline__ unsigned short f2bfu(float f) {
    return __builtin_bit_cast(unsigned short, (__bf16)f);
}

__device__ __forceinline__ f32x4 vmax4(f32x4 a, f32x4 b) {
#if __has_builtin(__builtin_elementwise_max)
    return __builtin_elementwise_max(a, b);
#else
    f32x4 r;
    r[0] = fmaxf(a[0], b[0]); r[1] = fmaxf(a[1], b[1]);
    r[2] = fmaxf(a[2], b[2]); r[3] = fmaxf(a[3], b[3]);
    return r;
#endif
}

__device__ __forceinline__ void gll16(const unsigned short* g, unsigned short* l) {
    __builtin_amdgcn_global_load_lds(
        (const __attribute__((address_space(1))) unsigned int*)g,
        (__attribute__((address_space(3))) unsigned int*)l, 16, 0, 0);
}

// LDS-only barrier: drains lgkm (LDS writes visible) but NOT vmcnt, so
// outstanding global_load_lds prefetches survive.
__device__ __forceinline__ void lds_barrier() {
    asm volatile("s_waitcnt lgkmcnt(0)" ::: "memory");
    __builtin_amdgcn_s_barrier();
    asm volatile("" ::: "memory");
}

// fp32 W -> bf16 PRE-SWIZZLED image: img[c][r*64 + (k ^ ((r&7)<<3))] = W[c][r][k]
// so a lane-linear global_load_lds copy reproduces the swizzled LDS layout.
__global__ void wconv_kernel(const float* __restrict__ w,
                             unsigned short* __restrict__ o) {
    int i = blockIdx.x * blockDim.x + threadIdx.x;   // one 8-elem chunk each
    if (i >= NCONN * 512) return;
    int conn = i >> 9;
    int within = i & 511;
    int r  = within >> 3;
    int k0 = (within & 7) << 3;
    const float* src = w + conn * MAT_ELEMS + r * DD + k0;
    float4 v0 = *reinterpret_cast<const float4*>(src);
    float4 v1 = *reinterpret_cast<const float4*>(src + 4);
    u16x8 d;
    d[0] = f2bfu(v0.x); d[1] = f2bfu(v0.y); d[2] = f2bfu(v0.z); d[3] = f2bfu(v0.w);
    d[4] = f2bfu(v1.x); d[5] = f2bfu(v1.y); d[6] = f2bfu(v1.z); d[7] = f2bfu(v1.w);
    *reinterpret_cast<u16x8*>(o + conn * MAT_ELEMS + r * DD + (k0 ^ ((r & 7) << 3))) = d;
}

template <bool GLL>
__global__ __launch_bounds__(THREADS, 3)
void dag_kernel(const float* __restrict__ x,
                const float* __restrict__ Wf,
                const unsigned short* __restrict__ Wimg,
                const float* __restrict__ bs,
                float* __restrict__ out) {
    __shared__ __align__(16) unsigned short ring[4 * MAT_ELEMS];    // 32 KB
    __shared__ __align__(16) unsigned short sB[2 * 2048];           //  8 KB: 4 KB/pair
    __shared__ __align__(16) float sBias[NCONN * DD];               //  7 KB

    const int tid  = threadIdx.x;
    const int lane = tid & 63;
    const int wv   = tid >> 6;
    const int pair = wv >> 1;     // 0,1
    const int h    = wv & 1;      // feature half
    const int l15  = lane & 15;
    const int kg   = lane >> 4;

    // ---- one-time prologue: bias -> LDS ----
    for (int idx = tid; idx < NCONN * DD / 4; idx += THREADS)
        reinterpret_cast<float4*>(sBias)[idx] = reinterpret_cast<const float4*>(bs)[idx];

    auto stage_gll = [&](int p) {
        const unsigned short* src = Wimg + CONN[p] * MAT_ELEMS + wv * 512 + lane * 8;
        unsigned short* dst = ring + (p & 3) * MAT_ELEMS + wv * 512;
#pragma unroll
        for (int hh = 0; hh < 2; ++hh)
            gll16(src + hh * 2048, dst + hh * 2048);
    };
    auto stage_direct = [&](int p) {   // fallback: fp32 -> bf16 reg staging
        const float* wp = Wf + CONN[p] * MAT_ELEMS;
#pragma unroll
        for (int hh = 0; hh < 2; ++hh) {
            const int e0 = hh * 2048 + tid * 8;
            float4 a0 = *reinterpret_cast<const float4*>(wp + e0);
            float4 a1 = *reinterpret_cast<const float4*>(wp + e0 + 4);
            u16x8 d;
            d[0] = f2bfu(a0.x); d[1] = f2bfu(a0.y); d[2] = f2bfu(a0.z); d[3] = f2bfu(a0.w);
            d[4] = f2bfu(a1.x); d[5] = f2bfu(a1.y); d[6] = f2bfu(a1.z); d[7] = f2bfu(a1.w);
            const int r = e0 >> 6, k0 = e0 & 63;
            *reinterpret_cast<u16x8*>(ring + (p & 3) * MAT_ELEMS +
                                      r * DD + (k0 ^ ((r & 7) << 3))) = d;
        }
    };

    if constexpr (GLL) { stage_gll(0); stage_gll(1); }
    __syncthreads();   // bias published; prologue glls drained; slots 0,1 ready

    unsigned short* myPB = sB + pair * 2048;   // pair-shared 32x64 bf16 bounce
    bf16x8 afrag[7][2][2];   // [src layer][row tile][k step]
    f32x4 acc[2][2];         // [row tile][feat tile within half]

    // ---- persistent grid-stride tile loop; ring schedule wraps seamlessly ----
    for (int tile = blockIdx.x; tile < NTILES; tile += GRIDB) {
        const bool has_next = (tile + GRIDB < NTILES);
        const long rowbase = (long)tile * ROWS_PER_TILE + pair * 32;

        // x -> afrag[0]; issued before the p=0 barrier so latency overlaps it
#pragma unroll
        for (int rt = 0; rt < 2; ++rt) {
            const float* xr = x + (rowbase + rt * 16 + l15) * DD;
#pragma unroll
            for (int s = 0; s < 2; ++s) {
                float4 v0 = *reinterpret_cast<const float4*>(xr + s * 32 + kg * 8);
                float4 v1 = *reinterpret_cast<const float4*>(xr + s * 32 + kg * 8 + 4);
                bf16x8 f;
                f[0] = (__bf16)v0.x; f[1] = (__bf16)v0.y; f[2] = (__bf16)v0.z; f[3] = (__bf16)v0.w;
                f[4] = (__bf16)v1.x; f[5] = (__bf16)v1.y; f[6] = (__bf16)v1.z; f[7] = (__bf16)v1.w;
                afrag[0][rt][s] = f;
            }
        }

#pragma unroll
        for (int j = 1; j <= 7; ++j) {
#pragma unroll
            for (int rt = 0; rt < 2; ++rt)
#pragma unroll
                for (int t = 0; t < 2; ++t) {
                    acc[rt][t][0] = 0.f; acc[rt][t][1] = 0.f;
                    acc[rt][t][2] = 0.f; acc[rt][t][3] = 0.f;
                }

#pragma unroll
            for (int i = 0; i < j; ++i) {
                const int p = j * (j - 1) / 2 + i;      // compute position 0..27
                const int c = OFFS[i] + (j - i - 1);    // connection index

                if constexpr (GLL) {
                    // pair periods; __syncthreads' vmcnt(0) drains exactly the
                    // glls staged one period ago (nothing newer outstanding).
                    // p=26 stages NEXT TILE's conns (0,1): slots (28&3,29&3)
                    // == (0,1) -- the mod-4 ring wraps seamlessly across tiles.
                    if ((p & 1) == 0) {
                        __syncthreads();
                        if (p < 26) { stage_gll(p + 2); stage_gll(p + 3); }
                        else if (has_next) { stage_gll(0); stage_gll(1); }
                    }
                } else {
                    __syncthreads();
                    stage_direct(p);
                    __syncthreads();
                }

                const unsigned short* wsl = ring + (p & 3) * MAT_ELEMS;
                __builtin_amdgcn_s_setprio(1);
#pragma unroll
                for (int t = 0; t < 2; ++t) {
                    const int n  = h * 32 + t * 16 + l15;   // this wave's feature
                    const int xo = (n & 7) << 3;
                    u16x8 rw0 = *reinterpret_cast<const u16x8*>(wsl + n * DD + ((kg * 8) ^ xo));
                    u16x8 rw1 = *reinterpret_cast<const u16x8*>(wsl + n * DD + ((32 + kg * 8) ^ xo));
                    const float bv = sBias[c * DD + n];
                    const f32x4 b4 = {bv, bv, bv, bv};
#pragma unroll
                    for (int rt = 0; rt < 2; ++rt) {
                        f32x4 C = acc[rt][t] + b4;
                        C = __builtin_amdgcn_mfma_f32_16x16x32_bf16(
                                afrag[i][rt][0], __builtin_bit_cast(bf16x8, rw0), C, 0, 0, 0);
                        C = __builtin_amdgcn_mfma_f32_16x16x32_bf16(
                                afrag[i][rt][1], __builtin_bit_cast(bf16x8, rw1), C, 0, 0, 0);
                        acc[rt][t] = vmax4(C, acc[rt][t]);
                    }
                }
                __builtin_amdgcn_s_setprio(0);
            }

            if (j < 7) {
                // Pair bounce: each wave writes its 32-feature half of D (bf16,
                // XOR-swizzled); lgkm-only barrier keeps glls in flight.
#pragma unroll
                for (int rt = 0; rt < 2; ++rt)
#pragma unroll
                    for (int t = 0; t < 2; ++t) {
                        const int f = h * 32 + t * 16 + l15;
#pragma unroll
                        for (int q = 0; q < 4; ++q) {
                            const int mr = rt * 16 + kg * 4 + q;
                            myPB[mr * DD + (f ^ ((mr & 7) << 3))] = f2bfu(acc[rt][t][q]);
                        }
                    }
                lds_barrier();   // pair writes visible; vmcnt NOT drained
#pragma unroll
                for (int rt = 0; rt < 2; ++rt)
#pragma unroll
                    for (int s = 0; s < 2; ++s) {
                        u16x8 ra = *reinterpret_cast<const u16x8*>(
                            &myPB[(rt * 16 + l15) * DD + ((s * 32 + kg * 8) ^ ((l15 & 7) << 3))]);
                        afrag[j][rt][s] = __builtin_bit_cast(bf16x8, ra);
                    }
                lds_barrier();   // reads done before next phase reuses myPB
            } else {
                // epilogue stores; drained by next tile's p=0 __syncthreads
                float* orow = out + rowbase * DD;
#pragma unroll
                for (int rt = 0; rt < 2; ++rt)
#pragma unroll
                    for (int t = 0; t < 2; ++t)
#pragma unroll
                        for (int q = 0; q < 4; ++q)
                            orow[(rt * 16 + kg * 4 + q) * DD + h * 32 + t * 16 + l15] =
                                acc[rt][t][q];
            }
        }
    }
}

extern "C" void kernel_launch(void* const* d_in, const int* in_sizes, int n_in,
                              void* d_out, int out_size, void* d_ws, size_t ws_size,
                              hipStream_t stream) {
    const float* x  = (const float*)d_in[0];
    const float* Ws = (const float*)d_in[1];
    const float* bs = (const float*)d_in[2];
    float* out = (float*)d_out;

    const size_t wbf_bytes = (size_t)NCONN * MAT_ELEMS * sizeof(unsigned short);
    if (ws_size >= wbf_bytes) {
        unsigned short* wbf = (unsigned short*)d_ws;
        wconv_kernel<<<(NCONN * 512 + 255) / 256, 256, 0, stream>>>(Ws, wbf);
        dag_kernel<true><<<GRIDB, THREADS, 0, stream>>>(x, Ws, wbf, bs, out);
    } else {
        dag_kernel<false><<<GRIDB, THREADS, 0, stream>>>(x, Ws, nullptr, bs, out);
    }
}

// Round 12
// 213.493 us; speedup vs baseline: 1.0836x; 1.0836x over previous
//
#include <hip/hip_runtime.h>

// DAG MLP: L=8 layers, D=64, B=262144, 28 all-to-all forward connections.
// outs[j] += relu(outs[i] @ W_c^T + b_c), output = outs[7].
// v12 = v8 (best, 102us) with the W flow SPLIT ACROSS PIPES to relieve the
// saturated LDS pipe (~79us busy of v8's 102us wall, modeled from m134 costs):
//   - EVEN compute positions: W via 4-slot LDS ring, global_load_lds(16B)
//     from the pre-swizzled bf16 image (1 conn staged per pair, half of v8)
//   - ODD compute positions: W read global->VGPR from the SAME swizzled image
//     (L2-resident, 4x dwordx4/wave), ping-pong reg buffer prefetched ~1.5
//     pairs ahead; vector-memory pipe, zero LDS involvement
//   - bias in register ping-pong (no sBias LDS reads)
//   - rest identical to v8: 2 pairs x 32 rows, feature-split waves, pair
//     __syncthreads, setprio, MFMA-carried accumulation
//     C_in=acc; acc=max(D+b,acc) == acc+relu(S+b), lgkm-only bounce barriers.

#define DD 64
#define NCONN 28
#define THREADS 256
#define ROWS_PER_BLOCK 64      // 2 pairs * 32 rows
#define MAT_ELEMS 4096         // 64*64

typedef __bf16 bf16x8 __attribute__((ext_vector_type(8)));
typedef float f32x4 __attribute__((ext_vector_type(4)));
typedef unsigned short u16x8 __attribute__((ext_vector_type(8)));

// c(i->j) = OFFS[i] + (j-i-1); CONN[p] = connection at compute position p
// (phases j=1..7, sources i ascending within phase).
__device__ constexpr int OFFS[7] = {0, 7, 13, 18, 22, 25, 27};
__device__ constexpr int CONN[28] = {0, 1,7, 2,8,13, 3,9,14,18, 4,10,15,19,22,
                                     5,11,16,20,23,25, 6,12,17,21,24,26,27};

__device__ __forceinline__ unsigned short f2bfu(float f) {
    return __builtin_bit_cast(unsigned short, (__bf16)f);
}

__device__ __forceinline__ f32x4 vmax4(f32x4 a, f32x4 b) {
#if __has_builtin(__builtin_elementwise_max)
    return __builtin_elementwise_max(a, b);
#else
    f32x4 r;
    r[0] = fmaxf(a[0], b[0]); r[1] = fmaxf(a[1], b[1]);
    r[2] = fmaxf(a[2], b[2]); r[3] = fmaxf(a[3], b[3]);
    return r;
#endif
}

__device__ __forceinline__ void gll16(const unsigned short* g, unsigned short* l) {
    __builtin_amdgcn_global_load_lds(
        (const __attribute__((address_space(1))) unsigned int*)g,
        (__attribute__((address_space(3))) unsigned int*)l, 16, 0, 0);
}

// LDS-only barrier: drains lgkm (LDS writes visible) but NOT vmcnt.
__device__ __forceinline__ void lds_barrier() {
    asm volatile("s_waitcnt lgkmcnt(0)" ::: "memory");
    __builtin_amdgcn_s_barrier();
    asm volatile("" ::: "memory");
}

// fp32 W -> bf16 PRE-SWIZZLED image: img[c][r*64 + (k ^ ((r&7)<<3))] = W[c][r][k]
// Both the lane-linear gll copy AND the direct global reads use this layout.
__global__ void wconv_kernel(const float* __restrict__ w,
                             unsigned short* __restrict__ o) {
    int i = blockIdx.x * blockDim.x + threadIdx.x;   // one 8-elem chunk each
    if (i >= NCONN * 512) return;
    int conn = i >> 9;
    int within = i & 511;
    int r  = within >> 3;
    int k0 = (within & 7) << 3;
    const float* src = w + conn * MAT_ELEMS + r * DD + k0;
    float4 v0 = *reinterpret_cast<const float4*>(src);
    float4 v1 = *reinterpret_cast<const float4*>(src + 4);
    u16x8 d;
    d[0] = f2bfu(v0.x); d[1] = f2bfu(v0.y); d[2] = f2bfu(v0.z); d[3] = f2bfu(v0.w);
    d[4] = f2bfu(v1.x); d[5] = f2bfu(v1.y); d[6] = f2bfu(v1.z); d[7] = f2bfu(v1.w);
    *reinterpret_cast<u16x8*>(o + conn * MAT_ELEMS + r * DD + (k0 ^ ((r & 7) << 3))) = d;
}

template <bool GLL>
__global__ __launch_bounds__(THREADS, 3)
void dag_kernel(const float* __restrict__ x,
                const float* __restrict__ Wf,
                const unsigned short* __restrict__ Wimg,
                const float* __restrict__ bs,
                float* __restrict__ out) {
    __shared__ __align__(16) unsigned short ring[4 * MAT_ELEMS];    // 32 KB
    __shared__ __align__(16) unsigned short sB[2 * 2048];           //  8 KB: 4 KB/pair
    // total 40 KB

    const int tid  = threadIdx.x;
    const int lane = tid & 63;
    const int wv   = tid >> 6;
    const int pair = wv >> 1;     // 0,1
    const int h    = wv & 1;      // feature half
    const int l15  = lane & 15;
    const int kg   = lane >> 4;

    const long rowbase = (long)blockIdx.x * ROWS_PER_BLOCK + pair * 32;

    // ---- x -> afrag[0] ----
    bf16x8 afrag[7][2][2];   // [src layer][row tile][k step]
#pragma unroll
    for (int rt = 0; rt < 2; ++rt) {
        const float* xr = x + (rowbase + rt * 16 + l15) * DD;
#pragma unroll
        for (int s = 0; s < 2; ++s) {
            float4 v0 = *reinterpret_cast<const float4*>(xr + s * 32 + kg * 8);
            float4 v1 = *reinterpret_cast<const float4*>(xr + s * 32 + kg * 8 + 4);
            bf16x8 f;
            f[0] = (__bf16)v0.x; f[1] = (__bf16)v0.y; f[2] = (__bf16)v0.z; f[3] = (__bf16)v0.w;
            f[4] = (__bf16)v1.x; f[5] = (__bf16)v1.y; f[6] = (__bf16)v1.z; f[7] = (__bf16)v1.w;
            afrag[0][rt][s] = f;
        }
    }

    // Bias ping-pong: breg[pair parity][conn in pair][t]; compile-time indices.
    float breg[2][2][2];
    auto loadBias = [&](int p) {
        const float* bp = bs + CONN[p] * DD + h * 32 + l15;
        float* b = breg[(p >> 1) & 1][p & 1];
        b[0] = bp[0]; b[1] = bp[16];
    };

    // W register ping-pong for ODD positions: wreg*[t*2+s], this wave's half.
    u16x8 wregA[4], wregB[4];
    auto loadWreg = [&](int p, u16x8* dst) {
        const unsigned short* base = Wimg + CONN[p] * MAT_ELEMS;
#pragma unroll
        for (int t = 0; t < 2; ++t) {
            const int n  = h * 32 + t * 16 + l15;
            const int xo = (n & 7) << 3;
#pragma unroll
            for (int s = 0; s < 2; ++s)
                dst[t * 2 + s] = *reinterpret_cast<const u16x8*>(
                    base + n * DD + (((s * 32 + kg * 8)) ^ xo));
        }
    };

    // EVEN positions: gll staging; pair P (positions 2P,2P+1) -> slot P&3.
    auto stage_gll = [&](int p) {
        const unsigned short* src = Wimg + CONN[p] * MAT_ELEMS + wv * 512 + lane * 8;
        unsigned short* dst = ring + ((p >> 1) & 3) * MAT_ELEMS + wv * 512;
#pragma unroll
        for (int hh = 0; hh < 2; ++hh)
            gll16(src + hh * 2048, dst + hh * 2048);
    };
    auto stage_direct = [&](int p) {   // fallback: fp32 -> bf16 reg staging, slot p&3
        const float* wp = Wf + CONN[p] * MAT_ELEMS;
#pragma unroll
        for (int hh = 0; hh < 2; ++hh) {
            const int e0 = hh * 2048 + tid * 8;
            float4 a0 = *reinterpret_cast<const float4*>(wp + e0);
            float4 a1 = *reinterpret_cast<const float4*>(wp + e0 + 4);
            u16x8 d;
            d[0] = f2bfu(a0.x); d[1] = f2bfu(a0.y); d[2] = f2bfu(a0.z); d[3] = f2bfu(a0.w);
            d[4] = f2bfu(a1.x); d[5] = f2bfu(a1.y); d[6] = f2bfu(a1.z); d[7] = f2bfu(a1.w);
            const int r = e0 >> 6, k0 = e0 & 63;
            *reinterpret_cast<u16x8*>(ring + (p & 3) * MAT_ELEMS +
                                      r * DD + (k0 ^ ((r & 7) << 3))) = d;
        }
    };

    loadBias(0); loadBias(1);
    if constexpr (GLL) { stage_gll(0); stage_gll(2); loadWreg(1, wregA); }
    __syncthreads();   // prologue loads drained; slots for pairs 0,1 ready

    unsigned short* myPB = sB + pair * 2048;   // pair-shared 32x64 bf16 bounce
    f32x4 acc[2][2];   // [row tile][feat tile within half]

#pragma unroll
    for (int j = 1; j <= 7; ++j) {
#pragma unroll
        for (int rt = 0; rt < 2; ++rt)
#pragma unroll
            for (int t = 0; t < 2; ++t) {
                acc[rt][t][0] = 0.f; acc[rt][t][1] = 0.f;
                acc[rt][t][2] = 0.f; acc[rt][t][3] = 0.f;
            }

#pragma unroll
        for (int i = 0; i < j; ++i) {
            const int p = j * (j - 1) / 2 + i;      // compute position 0..27

            if constexpr (GLL) {
                if ((p & 1) == 0) {
                    // pair-P start: barrier publishes slot P (staged 2 pairs ago)
                    if (p > 0) __syncthreads();
                    if (p + 4 <= 26) stage_gll(p + 4);                  // even of pair P+2
                    if (p + 2 < NCONN) { loadBias(p + 2); loadBias(p + 3); }
                    if (p + 3 < NCONN)                                   // odd of pair P+1
                        loadWreg(p + 3, (((p >> 1) + 1) & 1) ? wregB : wregA);
                }
            } else {
                __syncthreads();
                stage_direct(p);
                loadBias(p);
                __syncthreads();
            }

            const float* bv = breg[(p >> 1) & 1][p & 1];
            __builtin_amdgcn_s_setprio(1);
#pragma unroll
            for (int t = 0; t < 2; ++t) {
                u16x8 rw0, rw1;
                if (!GLL || (p & 1) == 0) {
                    const unsigned short* wsl =
                        ring + (GLL ? ((p >> 1) & 3) : (p & 3)) * MAT_ELEMS;
                    const int n  = h * 32 + t * 16 + l15;
                    const int xo = (n & 7) << 3;
                    rw0 = *reinterpret_cast<const u16x8*>(wsl + n * DD + ((kg * 8) ^ xo));
                    rw1 = *reinterpret_cast<const u16x8*>(wsl + n * DD + ((32 + kg * 8) ^ xo));
                } else {
                    const u16x8* wb = ((p >> 1) & 1) ? wregB : wregA;
                    rw0 = wb[t * 2 + 0]; rw1 = wb[t * 2 + 1];
                }
                const f32x4 b4 = {bv[t], bv[t], bv[t], bv[t]};
#pragma unroll
                for (int rt = 0; rt < 2; ++rt) {
                    f32x4 C = acc[rt][t];
                    C = __builtin_amdgcn_mfma_f32_16x16x32_bf16(
                            afrag[i][rt][0], __builtin_bit_cast(bf16x8, rw0), C, 0, 0, 0);
                    C = __builtin_amdgcn_mfma_f32_16x16x32_bf16(
                            afrag[i][rt][1], __builtin_bit_cast(bf16x8, rw1), C, 0, 0, 0);
                    acc[rt][t] = vmax4(C + b4, acc[rt][t]);
                }
            }
            __builtin_amdgcn_s_setprio(0);
        }

        if (j < 7) {
            // Pair bounce: each wave writes its 32-feature half of D (bf16,
            // XOR-swizzled); lgkm-only barrier keeps vector loads in flight.
#pragma unroll
            for (int rt = 0; rt < 2; ++rt)
#pragma unroll
                for (int t = 0; t < 2; ++t) {
                    const int f = h * 32 + t * 16 + l15;
#pragma unroll
                    for (int q = 0; q < 4; ++q) {
                        const int mr = rt * 16 + kg * 4 + q;
                        myPB[mr * DD + (f ^ ((mr & 7) << 3))] = f2bfu(acc[rt][t][q]);
                    }
                }
            lds_barrier();   // pair writes visible; vmcnt NOT drained
#pragma unroll
            for (int rt = 0; rt < 2; ++rt)
#pragma unroll
                for (int s = 0; s < 2; ++s) {
                    u16x8 ra = *reinterpret_cast<const u16x8*>(
                        &myPB[(rt * 16 + l15) * DD + ((s * 32 + kg * 8) ^ ((l15 & 7) << 3))]);
                    afrag[j][rt][s] = __builtin_bit_cast(bf16x8, ra);
                }
            lds_barrier();   // reads done before next phase reuses myPB
        } else {
            float* orow = out + rowbase * DD;
#pragma unroll
            for (int rt = 0; rt < 2; ++rt)
#pragma unroll
                for (int t = 0; t < 2; ++t)
#pragma unroll
                    for (int q = 0; q < 4; ++q)
                        orow[(rt * 16 + kg * 4 + q) * DD + h * 32 + t * 16 + l15] =
                            acc[rt][t][q];
        }
    }
}

extern "C" void kernel_launch(void* const* d_in, const int* in_sizes, int n_in,
                              void* d_out, int out_size, void* d_ws, size_t ws_size,
                              hipStream_t stream) {
    const float* x  = (const float*)d_in[0];
    const float* Ws = (const float*)d_in[1];
    const float* bs = (const float*)d_in[2];
    float* out = (float*)d_out;

    const int nrows = in_sizes[0] / DD;            // 262144
    const int grid  = nrows / ROWS_PER_BLOCK;      // 4096

    const size_t wbf_bytes = (size_t)NCONN * MAT_ELEMS * sizeof(unsigned short);
    if (ws_size >= wbf_bytes) {
        unsigned short* wbf = (unsigned short*)d_ws;
        wconv_kernel<<<(NCONN * 512 + 255) / 256, 256, 0, stream>>>(Ws, wbf);
        dag_kernel<true><<<grid, THREADS, 0, stream>>>(x, Ws, wbf, bs, out);
    } else {
        dag_kernel<false><<<grid, THREADS, 0, stream>>>(x, Ws, nullptr, bs, out);
    }
}

// Round 13
// 122.174 us; speedup vs baseline: 1.8935x; 1.7474x over previous
//
#include <hip/hip_runtime.h>

// DAG MLP: L=8 layers, D=64, B=262144, 28 all-to-all forward connections.
// outs[j] += relu(outs[i] @ W_c^T + b_c), output = outs[7].
// v13 = v8 (best, 102us) with the D->A bounce DESYNCHRONIZED:
//   - bounce WRITES at end of phase j (no barrier after them)
//   - bounce READS moved into phase j+1, right after its first existing
//     __syncthreads (whose lgkm+vm drain publishes the writes for free);
//     afrag[j] is only needed by conn i=j, the LAST conn of phase j+1,
//     so the read latency hides under 1-5 conns of MFMA work.
//   - bounce double-buffered by phase parity -> all 12 lds_barriers of v8
//     are deleted; block-wide syncs drop 26 -> 14 per tile.
//   - bias in register ping-pong (no sBias LDS stage, no LDS bias reads).
//   - rest identical to v8: 2 pairs x 32 rows, feature-split waves, 4-slot
//     LDS ring, pair __syncthreads, pre-swizzled bf16 W image via
//     global_load_lds(16B), setprio, MFMA-carried accumulation
//     C_in=acc; acc=max(D+b,acc) == acc+relu(S+b).

#define DD 64
#define NCONN 28
#define THREADS 256
#define ROWS_PER_BLOCK 64      // 2 pairs * 32 rows
#define MAT_ELEMS 4096         // 64*64

typedef __bf16 bf16x8 __attribute__((ext_vector_type(8)));
typedef float f32x4 __attribute__((ext_vector_type(4)));
typedef unsigned short u16x8 __attribute__((ext_vector_type(8)));

// c(i->j) = OFFS[i] + (j-i-1); CONN[p] = connection at compute position p
// (phases j=1..7, sources i ascending within phase).
__device__ constexpr int OFFS[7] = {0, 7, 13, 18, 22, 25, 27};
__device__ constexpr int CONN[28] = {0, 1,7, 2,8,13, 3,9,14,18, 4,10,15,19,22,
                                     5,11,16,20,23,25, 6,12,17,21,24,26,27};

__device__ __forceinline__ unsigned short f2bfu(float f) {
    return __builtin_bit_cast(unsigned short, (__bf16)f);
}

__device__ __forceinline__ f32x4 vmax4(f32x4 a, f32x4 b) {
#if __has_builtin(__builtin_elementwise_max)
    return __builtin_elementwise_max(a, b);
#else
    f32x4 r;
    r[0] = fmaxf(a[0], b[0]); r[1] = fmaxf(a[1], b[1]);
    r[2] = fmaxf(a[2], b[2]); r[3] = fmaxf(a[3], b[3]);
    return r;
#endif
}

__device__ __forceinline__ void gll16(const unsigned short* g, unsigned short* l) {
    __builtin_amdgcn_global_load_lds(
        (const __attribute__((address_space(1))) unsigned int*)g,
        (__attribute__((address_space(3))) unsigned int*)l, 16, 0, 0);
}

// fp32 W -> bf16 PRE-SWIZZLED image: img[c][r*64 + (k ^ ((r&7)<<3))] = W[c][r][k]
// so a lane-linear global_load_lds copy reproduces the swizzled LDS layout.
__global__ void wconv_kernel(const float* __restrict__ w,
                             unsigned short* __restrict__ o) {
    int i = blockIdx.x * blockDim.x + threadIdx.x;   // one 8-elem chunk each
    if (i >= NCONN * 512) return;
    int conn = i >> 9;
    int within = i & 511;
    int r  = within >> 3;
    int k0 = (within & 7) << 3;
    const float* src = w + conn * MAT_ELEMS + r * DD + k0;
    float4 v0 = *reinterpret_cast<const float4*>(src);
    float4 v1 = *reinterpret_cast<const float4*>(src + 4);
    u16x8 d;
    d[0] = f2bfu(v0.x); d[1] = f2bfu(v0.y); d[2] = f2bfu(v0.z); d[3] = f2bfu(v0.w);
    d[4] = f2bfu(v1.x); d[5] = f2bfu(v1.y); d[6] = f2bfu(v1.z); d[7] = f2bfu(v1.w);
    *reinterpret_cast<u16x8*>(o + conn * MAT_ELEMS + r * DD + (k0 ^ ((r & 7) << 3))) = d;
}

template <bool GLL>
__global__ __launch_bounds__(THREADS, 3)
void dag_kernel(const float* __restrict__ x,
                const float* __restrict__ Wf,
                const unsigned short* __restrict__ Wimg,
                const float* __restrict__ bs,
                float* __restrict__ out) {
    __shared__ __align__(16) unsigned short ring[4 * MAT_ELEMS];    // 32 KB
    __shared__ __align__(16) unsigned short sB[2 * 2 * 2048];       // 16 KB: pair x dbuf
    // total 48 KB -> 3 blocks/CU

    const int tid  = threadIdx.x;
    const int lane = tid & 63;
    const int wv   = tid >> 6;
    const int pair = wv >> 1;     // 0,1
    const int h    = wv & 1;      // feature half
    const int l15  = lane & 15;
    const int kg   = lane >> 4;

    const long rowbase = (long)blockIdx.x * ROWS_PER_BLOCK + pair * 32;

    // ---- x -> afrag[0] ----
    bf16x8 afrag[7][2][2];   // [src layer][row tile][k step]
#pragma unroll
    for (int rt = 0; rt < 2; ++rt) {
        const float* xr = x + (rowbase + rt * 16 + l15) * DD;
#pragma unroll
        for (int s = 0; s < 2; ++s) {
            float4 v0 = *reinterpret_cast<const float4*>(xr + s * 32 + kg * 8);
            float4 v1 = *reinterpret_cast<const float4*>(xr + s * 32 + kg * 8 + 4);
            bf16x8 f;
            f[0] = (__bf16)v0.x; f[1] = (__bf16)v0.y; f[2] = (__bf16)v0.z; f[3] = (__bf16)v0.w;
            f[4] = (__bf16)v1.x; f[5] = (__bf16)v1.y; f[6] = (__bf16)v1.z; f[7] = (__bf16)v1.w;
            afrag[0][rt][s] = f;
        }
    }

    // Bias ping-pong: breg[pair parity][conn in pair][t]; indices fold to
    // constants in the fully-unrolled loop.
    float breg[2][2][2];
    auto loadBias = [&](int p) {
        const float* bp = bs + CONN[p] * DD + h * 32 + l15;
        float* b = breg[(p >> 1) & 1][p & 1];
        b[0] = bp[0]; b[1] = bp[16];
    };

    auto stage_gll = [&](int p) {
        const unsigned short* src = Wimg + CONN[p] * MAT_ELEMS + wv * 512 + lane * 8;
        unsigned short* dst = ring + (p & 3) * MAT_ELEMS + wv * 512;
#pragma unroll
        for (int hh = 0; hh < 2; ++hh)
            gll16(src + hh * 2048, dst + hh * 2048);
    };
    auto stage_direct = [&](int p) {   // fallback: fp32 -> bf16 reg staging
        const float* wp = Wf + CONN[p] * MAT_ELEMS;
#pragma unroll
        for (int hh = 0; hh < 2; ++hh) {
            const int e0 = hh * 2048 + tid * 8;
            float4 a0 = *reinterpret_cast<const float4*>(wp + e0);
            float4 a1 = *reinterpret_cast<const float4*>(wp + e0 + 4);
            u16x8 d;
            d[0] = f2bfu(a0.x); d[1] = f2bfu(a0.y); d[2] = f2bfu(a0.z); d[3] = f2bfu(a0.w);
            d[4] = f2bfu(a1.x); d[5] = f2bfu(a1.y); d[6] = f2bfu(a1.z); d[7] = f2bfu(a1.w);
            const int r = e0 >> 6, k0 = e0 & 63;
            *reinterpret_cast<u16x8*>(ring + (p & 3) * MAT_ELEMS +
                                      r * DD + (k0 ^ ((r & 7) << 3))) = d;
        }
    };

    loadBias(0); loadBias(1);
    if constexpr (GLL) { stage_gll(0); stage_gll(1); }
    __syncthreads();   // prologue glls + bias in flight drained; slots 0,1 ready

    unsigned short* myPB = sB + pair * 4096;   // [2 bufs][2048] per pair
    f32x4 acc[2][2];   // [row tile][feat tile within half]

#pragma unroll
    for (int j = 1; j <= 7; ++j) {
        const int T = j * (j - 1) / 2;          // phase start position
#pragma unroll
        for (int rt = 0; rt < 2; ++rt)
#pragma unroll
            for (int t = 0; t < 2; ++t) {
                acc[rt][t][0] = 0.f; acc[rt][t][1] = 0.f;
                acc[rt][t][2] = 0.f; acc[rt][t][3] = 0.f;
            }

#pragma unroll
        for (int i = 0; i < j; ++i) {
            const int p = T + i;                // compute position 0..27

            if constexpr (GLL) {
                if ((p & 1) == 0) {
                    // pair schedule: barrier publishes slots p,p+1 (staged 2
                    // conns ago) AND the bounce writes from the previous phase.
                    if (p > 0) __syncthreads();
                    if (p + 2 < NCONN) { loadBias(p + 2); loadBias(p + 3); }
                    if (p + 2 < NCONN) { stage_gll(p + 2); stage_gll(p + 3); }
                }
            } else {
                __syncthreads();
                stage_direct(p);
                loadBias(p);
                __syncthreads();
            }

            // Deferred bounce READ: afrag[j-1] from buf[(j-1)&1], placed at
            // the first even position of this phase (after its barrier).
            // Needed only by conn i=j-1 (the last of this phase) -> its
            // ~120cy ds_read latency hides under the preceding conns' MFMAs.
            if (j >= 2 && p == T + (GLL ? (T & 1) : 0)) {
                const unsigned short* rb = myPB + ((j - 1) & 1) * 2048;
#pragma unroll
                for (int rt = 0; rt < 2; ++rt)
#pragma unroll
                    for (int s = 0; s < 2; ++s) {
                        u16x8 ra = *reinterpret_cast<const u16x8*>(
                            &rb[(rt * 16 + l15) * DD +
                                ((s * 32 + kg * 8) ^ ((l15 & 7) << 3))]);
                        afrag[j - 1][rt][s] = __builtin_bit_cast(bf16x8, ra);
                    }
            }

            const unsigned short* wsl = ring + (p & 3) * MAT_ELEMS;
            const float* bv = breg[(p >> 1) & 1][p & 1];
            __builtin_amdgcn_s_setprio(1);
#pragma unroll
            for (int t = 0; t < 2; ++t) {
                const int n  = h * 32 + t * 16 + l15;   // this wave's feature
                const int xo = (n & 7) << 3;
                u16x8 rw0 = *reinterpret_cast<const u16x8*>(wsl + n * DD + ((kg * 8) ^ xo));
                u16x8 rw1 = *reinterpret_cast<const u16x8*>(wsl + n * DD + ((32 + kg * 8) ^ xo));
                const f32x4 b4 = {bv[t], bv[t], bv[t], bv[t]};
#pragma unroll
                for (int rt = 0; rt < 2; ++rt) {
                    f32x4 C = acc[rt][t];
                    C = __builtin_amdgcn_mfma_f32_16x16x32_bf16(
                            afrag[i][rt][0], __builtin_bit_cast(bf16x8, rw0), C, 0, 0, 0);
                    C = __builtin_amdgcn_mfma_f32_16x16x32_bf16(
                            afrag[i][rt][1], __builtin_bit_cast(bf16x8, rw1), C, 0, 0, 0);
                    acc[rt][t] = vmax4(C + b4, acc[rt][t]);
                }
            }
            __builtin_amdgcn_s_setprio(0);
        }

        if (j < 7) {
            // Bounce WRITE only (bf16, XOR-swizzled) into buf[j&1]; no barrier
            // here -- the next phase's __syncthreads publishes it, and the
            // double-buffer removes the read-before-rewrite hazard.
            unsigned short* wb = myPB + (j & 1) * 2048;
#pragma unroll
            for (int rt = 0; rt < 2; ++rt)
#pragma unroll
                for (int t = 0; t < 2; ++t) {
                    const int f = h * 32 + t * 16 + l15;
#pragma unroll
                    for (int q = 0; q < 4; ++q) {
                        const int mr = rt * 16 + kg * 4 + q;
                        wb[mr * DD + (f ^ ((mr & 7) << 3))] = f2bfu(acc[rt][t][q]);
                    }
                }
        } else {
            float* orow = out + rowbase * DD;
#pragma unroll
            for (int rt = 0; rt < 2; ++rt)
#pragma unroll
                for (int t = 0; t < 2; ++t)
#pragma unroll
                    for (int q = 0; q < 4; ++q)
                        orow[(rt * 16 + kg * 4 + q) * DD + h * 32 + t * 16 + l15] =
                            acc[rt][t][q];
        }
    }
}

extern "C" void kernel_launch(void* const* d_in, const int* in_sizes, int n_in,
                              void* d_out, int out_size, void* d_ws, size_t ws_size,
                              hipStream_t stream) {
    const float* x  = (const float*)d_in[0];
    const float* Ws = (const float*)d_in[1];
    const float* bs = (const float*)d_in[2];
    float* out = (float*)d_out;

    const int nrows = in_sizes[0] / DD;            // 262144
    const int grid  = nrows / ROWS_PER_BLOCK;      // 4096

    const size_t wbf_bytes = (size_t)NCONN * MAT_ELEMS * sizeof(unsigned short);
    if (ws_size >= wbf_bytes) {
        unsigned short* wbf = (unsigned short*)d_ws;
        wconv_kernel<<<(NCONN * 512 + 255) / 256, 256, 0, stream>>>(Ws, wbf);
        dag_kernel<true><<<grid, THREADS, 0, stream>>>(x, Ws, wbf, bs, out);
    } else {
        dag_kernel<false><<<grid, THREADS, 0, stream>>>(x, Ws, nullptr, bs, out);
    }
}

// Round 14
// 95.460 us; speedup vs baseline: 2.4234x; 1.2798x over previous
//
#include <hip/hip_runtime.h>

// DAG MLP: L=8 layers, D=64, B=262144, 28 all-to-all forward connections.
// outs[j] += relu(outs[i] @ W_c^T + b_c), output = outs[7].
// v14 = v8 (best, 102us; ~84% LDS-pipe-bound by m134 cost model) with three
// LDS-instruction cuts, structure otherwise identical:
//   1. bias in register ping-pong (no sBias stage, no LDS bias reads)
//   2. sigma k-permutation baked into the W image AND the x-load: within each
//      32-feature half, feature u <-> slot 2u(+1) interleave. MFMA is
//      invariant to k-permutation applied to BOTH operands. This makes each
//      lane's (n, n+16) acc pair slot-adjacent -> bounce writes become
//      8x {v_cvt_pk_bf16_f32 + ds_write_b32} instead of 16x ds_write_b16.
//   3. bounce double-buffered by phase parity -> the read-done lds_barrier
//      is removed (block-wide syncs 26 -> 20 per tile).
// Everything else byte-for-byte v8: 2 pairs x 32 rows, feature-split waves,
// 4-slot LDS ring, pair __syncthreads, global_load_lds(16B) from the
// pre-swizzled bf16 image, setprio, MFMA-carried accumulation
// C_in=acc; acc=max(D+b,acc) == acc+relu(S+b).

#define DD 64
#define NCONN 28
#define THREADS 256
#define ROWS_PER_BLOCK 64      // 2 pairs * 32 rows
#define MAT_ELEMS 4096         // 64*64

typedef __bf16 bf16x8 __attribute__((ext_vector_type(8)));
typedef float f32x4 __attribute__((ext_vector_type(4)));
typedef unsigned short u16x8 __attribute__((ext_vector_type(8)));

// c(i->j) = OFFS[i] + (j-i-1); CONN[p] = connection at compute position p
// (phases j=1..7, sources i ascending within phase).
__device__ constexpr int OFFS[7] = {0, 7, 13, 18, 22, 25, 27};
__device__ constexpr int CONN[28] = {0, 1,7, 2,8,13, 3,9,14,18, 4,10,15,19,22,
                                     5,11,16,20,23,25, 6,12,17,21,24,26,27};

__device__ __forceinline__ unsigned short f2bfu(float f) {
    return __builtin_bit_cast(unsigned short, (__bf16)f);
}

__device__ __forceinline__ f32x4 vmax4(f32x4 a, f32x4 b) {
#if __has_builtin(__builtin_elementwise_max)
    return __builtin_elementwise_max(a, b);
#else
    f32x4 r;
    r[0] = fmaxf(a[0], b[0]); r[1] = fmaxf(a[1], b[1]);
    r[2] = fmaxf(a[2], b[2]); r[3] = fmaxf(a[3], b[3]);
    return r;
#endif
}

__device__ __forceinline__ void gll16(const unsigned short* g, unsigned short* l) {
    __builtin_amdgcn_global_load_lds(
        (const __attribute__((address_space(1))) unsigned int*)g,
        (__attribute__((address_space(3))) unsigned int*)l, 16, 0, 0);
}

// LDS-only barrier: drains lgkm (LDS writes visible) but NOT vmcnt.
__device__ __forceinline__ void lds_barrier() {
    asm volatile("s_waitcnt lgkmcnt(0)" ::: "memory");
    __builtin_amdgcn_s_barrier();
    asm volatile("" ::: "memory");
}

// fp32 W -> bf16 image, sigma-PERMUTED and address-swizzled:
//   slot s (0..63) holds feature feat(s) = (s&32) + ((s&31)>>1) + (s&1)*16
//   img[c][n*64 + (s ^ ((n&7)<<3))] = W[c][n][feat(s)]
// A lane-linear global_load_lds copy reproduces this layout in LDS.
__global__ void wconv_kernel(const float* __restrict__ w,
                             unsigned short* __restrict__ o) {
    int i = blockIdx.x * blockDim.x + threadIdx.x;   // one 8-slot chunk each
    if (i >= NCONN * 512) return;
    int conn = i >> 9;
    int within = i & 511;
    int n  = within >> 3;
    int s0 = (within & 7) << 3;                      // slot octet base
    int fb = (s0 & 32) + ((s0 & 31) >> 1);           // feature base
    const float* src = w + conn * MAT_ELEMS + n * DD + fb;
    float4 v0 = *reinterpret_cast<const float4*>(src);        // feats fb..fb+3
    float4 v1 = *reinterpret_cast<const float4*>(src + 16);   // feats fb+16..+19
    u16x8 d;   // slot s0+e holds feature fb + (e>>1) + (e&1)*16
    d[0] = f2bfu(v0.x); d[1] = f2bfu(v1.x); d[2] = f2bfu(v0.y); d[3] = f2bfu(v1.y);
    d[4] = f2bfu(v0.z); d[5] = f2bfu(v1.z); d[6] = f2bfu(v0.w); d[7] = f2bfu(v1.w);
    *reinterpret_cast<u16x8*>(o + conn * MAT_ELEMS + n * DD + (s0 ^ ((n & 7) << 3))) = d;
}

template <bool GLL>
__global__ __launch_bounds__(THREADS, 3)
void dag_kernel(const float* __restrict__ x,
                const float* __restrict__ Wf,
                const unsigned short* __restrict__ Wimg,
                const float* __restrict__ bs,
                float* __restrict__ out) {
    __shared__ __align__(16) unsigned short ring[4 * MAT_ELEMS];    // 32 KB
    __shared__ __align__(16) unsigned short sB[2 * 2 * 2048];       // 16 KB: pair x dbuf
    // total 48 KB -> 3 blocks/CU

    const int tid  = threadIdx.x;
    const int lane = tid & 63;
    const int wv   = tid >> 6;
    const int pair = wv >> 1;     // 0,1
    const int h    = wv & 1;      // feature half
    const int l15  = lane & 15;
    const int kg   = lane >> 4;

    const long rowbase = (long)blockIdx.x * ROWS_PER_BLOCK + pair * 32;

    // ---- x -> afrag[0], sigma-ordered k slots ----
    // slot kg*8+e (within kstep s) = feature s*32 + kg*4 + (e>>1) + (e&1)*16
    bf16x8 afrag[7][2][2];   // [src layer][row tile][k step]
#pragma unroll
    for (int rt = 0; rt < 2; ++rt) {
        const float* xr = x + (rowbase + rt * 16 + l15) * DD;
#pragma unroll
        for (int s = 0; s < 2; ++s) {
            float4 v0 = *reinterpret_cast<const float4*>(xr + s * 32 + kg * 4);
            float4 v1 = *reinterpret_cast<const float4*>(xr + s * 32 + kg * 4 + 16);
            bf16x8 f;
            f[0] = (__bf16)v0.x; f[1] = (__bf16)v1.x; f[2] = (__bf16)v0.y; f[3] = (__bf16)v1.y;
            f[4] = (__bf16)v0.z; f[5] = (__bf16)v1.z; f[6] = (__bf16)v0.w; f[7] = (__bf16)v1.w;
            afrag[0][rt][s] = f;
        }
    }

    // Bias ping-pong: breg[pair parity][conn in pair][t]; compile-time indices.
    float breg[2][2][2];
    auto loadBias = [&](int p) {
        const float* bp = bs + CONN[p] * DD + h * 32 + l15;
        float* b = breg[(p >> 1) & 1][p & 1];
        b[0] = bp[0]; b[1] = bp[16];
    };

    auto stage_gll = [&](int p) {
        const unsigned short* src = Wimg + CONN[p] * MAT_ELEMS + wv * 512 + lane * 8;
        unsigned short* dst = ring + (p & 3) * MAT_ELEMS + wv * 512;
#pragma unroll
        for (int hh = 0; hh < 2; ++hh)
            gll16(src + hh * 2048, dst + hh * 2048);
    };
    auto stage_direct = [&](int p) {   // fallback: fp32 -> bf16, sigma + swizzle
        const float* wp = Wf + CONN[p] * MAT_ELEMS;
#pragma unroll
        for (int hh = 0; hh < 2; ++hh) {
            const int e0 = hh * 2048 + tid * 8;      // linear u16 index = n*64 + s0
            const int n  = e0 >> 6, s0 = e0 & 63;
            const int fb = (s0 & 32) + ((s0 & 31) >> 1);
            const float* srcp = wp + n * DD + fb;
            float4 a0 = *reinterpret_cast<const float4*>(srcp);
            float4 a1 = *reinterpret_cast<const float4*>(srcp + 16);
            u16x8 d;
            d[0] = f2bfu(a0.x); d[1] = f2bfu(a1.x); d[2] = f2bfu(a0.y); d[3] = f2bfu(a1.y);
            d[4] = f2bfu(a0.z); d[5] = f2bfu(a1.z); d[6] = f2bfu(a0.w); d[7] = f2bfu(a1.w);
            *reinterpret_cast<u16x8*>(ring + (p & 3) * MAT_ELEMS +
                                      n * DD + (s0 ^ ((n & 7) << 3))) = d;
        }
    };

    loadBias(0); loadBias(1);
    if constexpr (GLL) { stage_gll(0); stage_gll(1); }
    __syncthreads();   // prologue loads drained; slots 0,1 ready

    unsigned short* myPB = sB + pair * 4096;   // [2 bufs][2048 u16] per pair
    f32x4 acc[2][2];   // [row tile][feat tile within half]

#pragma unroll
    for (int j = 1; j <= 7; ++j) {
#pragma unroll
        for (int rt = 0; rt < 2; ++rt)
#pragma unroll
            for (int t = 0; t < 2; ++t) {
                acc[rt][t][0] = 0.f; acc[rt][t][1] = 0.f;
                acc[rt][t][2] = 0.f; acc[rt][t][3] = 0.f;
            }

#pragma unroll
        for (int i = 0; i < j; ++i) {
            const int p = j * (j - 1) / 2 + i;      // compute position 0..27

            if constexpr (GLL) {
                // pair schedule: barrier once per even p publishes slots p,p+1
                // (staged 2 conns ago) and the previous phase's bounce writes.
                if ((p & 1) == 0) {
                    if (p > 0) __syncthreads();
                    if (p + 2 < NCONN) { loadBias(p + 2); loadBias(p + 3); }
                    if (p + 2 < NCONN) { stage_gll(p + 2); stage_gll(p + 3); }
                }
            } else {
                __syncthreads();
                stage_direct(p);
                loadBias(p);
                __syncthreads();
            }

            const unsigned short* wsl = ring + (p & 3) * MAT_ELEMS;
            const float* bv = breg[(p >> 1) & 1][p & 1];
            __builtin_amdgcn_s_setprio(1);
#pragma unroll
            for (int t = 0; t < 2; ++t) {
                const int n  = h * 32 + t * 16 + l15;   // this wave's feature
                const int xo = (n & 7) << 3;
                u16x8 rw0 = *reinterpret_cast<const u16x8*>(wsl + n * DD + ((kg * 8) ^ xo));
                u16x8 rw1 = *reinterpret_cast<const u16x8*>(wsl + n * DD + ((32 + kg * 8) ^ xo));
                const f32x4 b4 = {bv[t], bv[t], bv[t], bv[t]};
#pragma unroll
                for (int rt = 0; rt < 2; ++rt) {
                    f32x4 C = acc[rt][t];
                    C = __builtin_amdgcn_mfma_f32_16x16x32_bf16(
                            afrag[i][rt][0], __builtin_bit_cast(bf16x8, rw0), C, 0, 0, 0);
                    C = __builtin_amdgcn_mfma_f32_16x16x32_bf16(
                            afrag[i][rt][1], __builtin_bit_cast(bf16x8, rw1), C, 0, 0, 0);
                    acc[rt][t] = vmax4(C + b4, acc[rt][t]);
                }
            }
            __builtin_amdgcn_s_setprio(0);
        }

        if (j < 7) {
            // Bounce into buf[j&1]: lane's (n, n+16) pair is sigma-adjacent ->
            // one cvt_pk + one b32 write per (rt,q). 8 writes/wave/phase.
            unsigned short* wb = myPB + (j & 1) * 2048;
            const int sp = h * 32 + 2 * l15;            // even slot of the pair
#pragma unroll
            for (int rt = 0; rt < 2; ++rt)
#pragma unroll
                for (int q = 0; q < 4; ++q) {
                    const int mr = rt * 16 + kg * 4 + q;
                    unsigned int pk;
                    asm("v_cvt_pk_bf16_f32 %0, %1, %2"
                        : "=v"(pk) : "v"(acc[rt][0][q]), "v"(acc[rt][1][q]));
                    *reinterpret_cast<unsigned int*>(
                        &wb[mr * DD + (sp ^ ((mr & 7) << 3))]) = pk;
                }
            lds_barrier();   // pair writes visible; vmcnt (glls) NOT drained
#pragma unroll
            for (int rt = 0; rt < 2; ++rt)
#pragma unroll
                for (int s = 0; s < 2; ++s) {
                    u16x8 ra = *reinterpret_cast<const u16x8*>(
                        &wb[(rt * 16 + l15) * DD + ((s * 32 + kg * 8) ^ ((l15 & 7) << 3))]);
                    afrag[j][rt][s] = __builtin_bit_cast(bf16x8, ra);
                }
            // no read-done barrier: next phase writes the OTHER buffer, and
            // its first __syncthreads orders the buffer swap across waves.
        } else {
            float* orow = out + rowbase * DD;
#pragma unroll
            for (int rt = 0; rt < 2; ++rt)
#pragma unroll
                for (int t = 0; t < 2; ++t)
#pragma unroll
                    for (int q = 0; q < 4; ++q)
                        orow[(rt * 16 + kg * 4 + q) * DD + h * 32 + t * 16 + l15] =
                            acc[rt][t][q];
        }
    }
}

extern "C" void kernel_launch(void* const* d_in, const int* in_sizes, int n_in,
                              void* d_out, int out_size, void* d_ws, size_t ws_size,
                              hipStream_t stream) {
    const float* x  = (const float*)d_in[0];
    const float* Ws = (const float*)d_in[1];
    const float* bs = (const float*)d_in[2];
    float* out = (float*)d_out;

    const int nrows = in_sizes[0] / DD;            // 262144
    const int grid  = nrows / ROWS_PER_BLOCK;      // 4096

    const size_t wbf_bytes = (size_t)NCONN * MAT_ELEMS * sizeof(unsigned short);
    if (ws_size >= wbf_bytes) {
        unsigned short* wbf = (unsigned short*)d_ws;
        wconv_kernel<<<(NCONN * 512 + 255) / 256, 256, 0, stream>>>(Ws, wbf);
        dag_kernel<true><<<grid, THREADS, 0, stream>>>(x, Ws, wbf, bs, out);
    } else {
        dag_kernel<false><<<grid, THREADS, 0, stream>>>(x, Ws, nullptr, bs, out);
    }
}